// Round 1
// 580.444 us; speedup vs baseline: 1.1481x; 1.1481x over previous
//
#include <hip/hip_runtime.h>
#include <math.h>

// GrapsuleNet forward, restructured:
//  K1 k_mean    : xm[b,c] = mean_n x[b,c,n]                      (reads x, 201MB)
//  K2 k_qk      : q = xm@qwT+qb; qk_t[b,c,h] = (1/4)*sum_d q*kw  (coalesced e-loop; kb dropped: softmax-invariant)
//  K3 k_logits  : logits[b,h,n] = sum_c x[b,c,n]*qk_t[b,c,h]     (reads x, 201MB; unroll 8 for MLP)
//  K4 k_softmax : attn (in-place over logits) + pos[b,h,2]
//  K5 k_xa      : xa partials = attn^T @ x  (reg-prefetch double buffer, 2 blocks/CU)
//  K6 k_values  : xa = sum 16 partials; values = xa@vwT+vb; msgv = values@msg_wT+msg_b
//  K7 k_agg     : per-dst aggregation over the 15 in-neighbors
//  K8 k_mlp     : silu MLP + layer_scale*o + values -> out
//
// Entire GNN branch is scaled by layer_scale=1e-6 before the residual, so __sinf/__expf
// precision there is irrelevant; the accuracy-critical path is values (f32).

#define Bsz 32
#define Cc  384
#define Nn  4096
#define Ee  256
#define NHh 16
#define HDd 16
#define HIDh 128

__device__ __forceinline__ float waveSum(float v){
#pragma unroll
  for(int o=32;o;o>>=1) v += __shfl_down(v,(unsigned)o,64);
  return v;
}
__device__ __forceinline__ float waveMax(float v){
#pragma unroll
  for(int o=32;o;o>>=1) v = fmaxf(v, __shfl_down(v,(unsigned)o,64));
  return v;
}
__device__ __forceinline__ float blockSum(float v, float* sm){
  int lane = threadIdx.x & 63, w = threadIdx.x >> 6;
  int nw = blockDim.x >> 6;
  float r = waveSum(v);
  if(lane==0) sm[w] = r;
  __syncthreads();
  float s = 0.f;
  for(int i=0;i<nw;i++) s += sm[i];
  __syncthreads();
  return s;
}
__device__ __forceinline__ float blockMax(float v, float* sm){
  int lane = threadIdx.x & 63, w = threadIdx.x >> 6;
  int nw = blockDim.x >> 6;
  float r = waveMax(v);
  if(lane==0) sm[w] = r;
  __syncthreads();
  float s = -1e30f;
  for(int i=0;i<nw;i++) s = fmaxf(s, sm[i]);
  __syncthreads();
  return s;
}

// ---------------- K1: mean over pixels ----------------
__global__ __launch_bounds__(256) void k_mean(const float* __restrict__ x, float* __restrict__ xm){
  int bc = blockIdx.x, t = threadIdx.x;
  const float4* xr = (const float4*)(x + (size_t)bc*Nn);
  float s = 0.f;
#pragma unroll
  for(int i=0;i<4;i++){ float4 v = xr[t + 256*i]; s += (v.x+v.y) + (v.z+v.w); }
  __shared__ float sm[8];
  s = blockSum(s, sm);
  if(t==0) xm[bc] = s * (1.0f/4096.0f);
}

// ---------------- K2: q and folded qk (coalesced kw reads) ----------------
// block = 384 threads; thread t owns column c = t of kw / qk_t.
__global__ __launch_bounds__(384) void k_qk(const float* __restrict__ xm, const float* __restrict__ qw,
                                            const float* __restrict__ qb, const float* __restrict__ kw,
                                            float* __restrict__ qk_t){
  int b = blockIdx.x, t = threadIdx.x;
  __shared__ float xs[Cc];
  __shared__ float qs[Ee];
  if(t < 96) ((float4*)xs)[t] = ((const float4*)(xm + b*Cc))[t];
  __syncthreads();
  if(t < Ee){ // q[e] = qb[e] + xm . qw[e,:]   (row-per-lane; 4KB line window -> L1-resident)
    const float4* wr = (const float4*)(qw + (size_t)t*Cc);
    const float4* xv = (const float4*)xs;
    float a = qb[t];
#pragma unroll 4
    for(int c4=0;c4<96;c4++){ float4 w = wr[c4], xx = xv[c4]; a += w.x*xx.x + w.y*xx.y + w.z*xx.z + w.w*xx.w; }
    qs[t] = a;
  }
  __syncthreads();
  // qk_t[(b*384+c)*16+h] = 0.25 * sum_d q[h*16+d]*kw[h*16+d, c]
  // kw loads coalesced over c = t (lane stride 4B). All acc indices static.
  int c = t;
#pragma unroll
  for(int hq=0; hq<4; hq++){
    float r0, r1, r2, r3;
#pragma unroll
    for(int hh=0; hh<4; hh++){
      int h = hq*4 + hh;
      float a = 0.f;
#pragma unroll
      for(int d=0; d<16; d++) a += qs[h*16+d] * kw[(size_t)(h*16+d)*Cc + c];
      a *= 0.25f;
      if(hh==0) r0=a; else if(hh==1) r1=a; else if(hh==2) r2=a; else r3=a;
    }
    ((float4*)(qk_t + ((size_t)b*Cc + c)*16))[hq] = make_float4(r0,r1,r2,r3);
  }
}

// ---------------- K3: logits ----------------
// unroll 8: 8 outstanding 256B/wave global loads -> latency-covered streaming.
__global__ __launch_bounds__(256) void k_logits(const float* __restrict__ x, const float* __restrict__ qk_t,
                                                float* __restrict__ lg){
  int b = blockIdx.y;
  int n = blockIdx.x*256 + threadIdx.x;
  float acc[16];
#pragma unroll
  for(int h=0;h<16;h++) acc[h] = 0.f;
  const float* xb = x + (size_t)b*Cc*Nn;
  const float4* qk = (const float4*)(qk_t + (size_t)b*Cc*16);
#pragma unroll 8
  for(int c=0;c<Cc;c++){
    float xv = xb[(size_t)c*Nn + n];            // coalesced, streamed once
    float4 q0 = qk[c*4+0], q1 = qk[c*4+1], q2 = qk[c*4+2], q3 = qk[c*4+3]; // wave-uniform -> s_load
    acc[0]  += xv*q0.x; acc[1]  += xv*q0.y; acc[2]  += xv*q0.z; acc[3]  += xv*q0.w;
    acc[4]  += xv*q1.x; acc[5]  += xv*q1.y; acc[6]  += xv*q1.z; acc[7]  += xv*q1.w;
    acc[8]  += xv*q2.x; acc[9]  += xv*q2.y; acc[10] += xv*q2.z; acc[11] += xv*q2.w;
    acc[12] += xv*q3.x; acc[13] += xv*q3.y; acc[14] += xv*q3.z; acc[15] += xv*q3.w;
  }
#pragma unroll
  for(int h=0;h<16;h++) lg[((size_t)(b*16+h))*Nn + n] = acc[h];
}

// ---------------- K4: softmax over n (in place) + pos ----------------
__global__ __launch_bounds__(256) void k_softmax(float* __restrict__ lg, float* __restrict__ pos){
  int node = blockIdx.x, t = threadIdx.x;
  __shared__ float sm[8];
  float4* gv = (float4*)(lg + (size_t)node*Nn);
  float4 vv[4];
  float m = -1e30f;
#pragma unroll
  for(int i=0;i<4;i++){
    vv[i] = gv[t + 256*i];
    m = fmaxf(m, fmaxf(fmaxf(vv[i].x, vv[i].y), fmaxf(vv[i].z, vv[i].w)));
  }
  m = blockMax(m, sm);
  float s = 0.f, px = 0.f, py = 0.f;
  float4 ev[4];
#pragma unroll
  for(int i=0;i<4;i++){
    int n0 = 4*(t + 256*i);
    float e0 = __expf(vv[i].x - m), e1 = __expf(vv[i].y - m);
    float e2 = __expf(vv[i].z - m), e3 = __expf(vv[i].w - m);
    float row = (float)(n0 >> 6);
    float c0  = (float)(n0 & 63);
    float es  = (e0+e1)+(e2+e3);
    s  += es;
    px += es * row;
    py += e0*c0 + e1*(c0+1.f) + e2*(c0+2.f) + e3*(c0+3.f);
    ev[i] = make_float4(e0,e1,e2,e3);
  }
  s  = blockSum(s,  sm);
  px = blockSum(px, sm);
  py = blockSum(py, sm);
  float inv = 1.0f / s;
#pragma unroll
  for(int i=0;i<4;i++)
    gv[t + 256*i] = make_float4(ev[i].x*inv, ev[i].y*inv, ev[i].z*inv, ev[i].w*inv);
  if(t==0){ pos[node*2] = px*inv; pos[node*2+1] = py*inv; }
}

// ---------------- K5: xa partials = attn^T @ x ----------------
// grid (16, b): n-range 256 = 8 chunks of 32; 2 blocks/CU (LDS 57.6KB).
// Register-prefetch double buffer: next chunk's global loads issued before compute.
// LDS rows padded to 36 floats (bank-safe, 16B aligned).
#define XROW 36
__global__ __launch_bounds__(256) void k_xa(const float* __restrict__ x, const float* __restrict__ attn,
                                            float* __restrict__ part){
  __shared__ float xl[Cc*XROW];    // 55.3 KB
  __shared__ float al[NHh*XROW];   // 2.3 KB
  int b = blockIdx.y, ns = blockIdx.x, t = threadIdx.x;
  int th = t & 3, tc = t >> 2;
  float acc[4][6];
#pragma unroll
  for(int k=0;k<4;k++)
#pragma unroll
    for(int m=0;m<6;m++) acc[k][m] = 0.f;

  float4 xr[12];
  float4 ar = make_float4(0,0,0,0);
  int ah = t >> 3, aj = t & 7;

  auto LOAD = [&](int ch){
    int n0 = ns*256 + ch*32;
    if(t < 128)
      ar = *(const float4*)(attn + ((size_t)(b*16+ah))*Nn + n0 + aj*4);
#pragma unroll
    for(int i=0;i<12;i++){
      int f = t + 256*i;
      int c = f >> 3, j4 = f & 7;
      xr[i] = *(const float4*)(x + ((size_t)(b*Cc+c))*Nn + n0 + j4*4);
    }
  };

  LOAD(0);
  for(int ch=0; ch<8; ch++){
    // commit current chunk's registers to LDS
    if(t < 128) *(float4*)(al + ah*XROW + aj*4) = ar;
#pragma unroll
    for(int i=0;i<12;i++){
      int f = t + 256*i;
      int c = f >> 3, j4 = f & 7;
      *(float4*)(xl + c*XROW + j4*4) = xr[i];
    }
    __syncthreads();
    if(ch < 7) LOAD(ch+1);           // issue next chunk; in flight under compute
#pragma unroll
    for(int j4=0;j4<8;j4++){
      float4 a4[4], x4[6];
#pragma unroll
      for(int k=0;k<4;k++) a4[k] = *(const float4*)(al + (th+4*k)*XROW + j4*4);
#pragma unroll
      for(int m=0;m<6;m++) x4[m] = *(const float4*)(xl + (tc+64*m)*XROW + j4*4);
#pragma unroll
      for(int k=0;k<4;k++)
#pragma unroll
        for(int m=0;m<6;m++)
          acc[k][m] += a4[k].x*x4[m].x + a4[k].y*x4[m].y + a4[k].z*x4[m].z + a4[k].w*x4[m].w;
    }
    __syncthreads();
  }
#pragma unroll
  for(int k=0;k<4;k++)
#pragma unroll
    for(int m=0;m<6;m++)
      part[(size_t)ns*(Bsz*NHh*Cc) + (size_t)(b*16 + th + 4*k)*Cc + (tc + 64*m)] = acc[k][m];
}

// ---------------- K6: xa reduce (16 partials) + values + msgv ----------------
__global__ __launch_bounds__(256) void k_values(const float* __restrict__ part, const float* __restrict__ vw,
                                                const float* __restrict__ vb, const float* __restrict__ msg_w,
                                                const float* __restrict__ msg_b,
                                                float* __restrict__ values, float* __restrict__ msgv){
  int node = blockIdx.x, t = threadIdx.x;
  __shared__ float xa[Cc];
  __shared__ float vs[Ee];
  if(t < 96){
    float4 s = make_float4(0,0,0,0);
#pragma unroll
    for(int p=0;p<16;p++){
      float4 v = *(const float4*)(part + (size_t)p*(Bsz*NHh*Cc) + (size_t)node*Cc + t*4);
      s.x += v.x; s.y += v.y; s.z += v.z; s.w += v.w;
    }
    *(float4*)(xa + t*4) = s;
  }
  __syncthreads();
  {
    const float4* wr = (const float4*)(vw + (size_t)t*Cc);
    const float4* xv = (const float4*)xa;
    float a = vb[t];
#pragma unroll 4
    for(int c4=0;c4<96;c4++){ float4 w = wr[c4], xx = xv[c4]; a += w.x*xx.x + w.y*xx.y + w.z*xx.z + w.w*xx.w; }
    values[(size_t)node*Ee + t] = a;
    vs[t] = a;
  }
  __syncthreads();
  if(t < HIDh){
    const float4* mr = (const float4*)(msg_w + (size_t)t*Ee);
    const float4* vv = (const float4*)vs;
    float a = msg_b[t];
#pragma unroll 4
    for(int e4=0;e4<64;e4++){ float4 w = mr[e4], xx = vv[e4]; a += w.x*xx.x + w.y*xx.y + w.z*xx.z + w.w*xx.w; }
    msgv[(size_t)node*HIDh + t] = a;
  }
}

// ---------------- K7: graph aggregation (mean over 15 in-neighbors) ----------------
__global__ __launch_bounds__(128) void k_agg(const float* __restrict__ pos, const float* __restrict__ msgv,
                                             const float* __restrict__ brff, const float* __restrict__ emb_w,
                                             float* __restrict__ agg){
  int node = blockIdx.x, t = threadIdx.x;
  int b = node >> 4, jj = node & 15;
  __shared__ float ps[32];
  __shared__ float bf[64];
  __shared__ float mv[16*HIDh];
  __shared__ float ea[64];
  if(t < 32) ps[t] = pos[b*32 + t];
  if(t < 64) bf[t] = brff[t];
#pragma unroll
  for(int i=0;i<4;i++){ int f = t + 128*i; ((float4*)mv)[f] = ((const float4*)(msgv + (size_t)b*16*HIDh))[f]; }
  float4 er[16];
#pragma unroll
  for(int i=0;i<16;i++) er[i] = ((const float4*)(emb_w + (size_t)t*64))[i];
  __syncthreads();
  float pxj = ps[jj*2], pyj = ps[jj*2+1];
  float acc = 0.f;
  for(int i=0;i<16;i++){
    if(i == jj) continue;            // jj is block-uniform: barriers stay aligned
    float rx = ps[i*2]   - pxj;
    float ry = ps[i*2+1] - pyj;
    __syncthreads();
    if(t < 32){
      float pr = rx*bf[t*2] + ry*bf[t*2+1];
      ea[t]    = 1.41421356f * __sinf(pr);
      ea[t+32] = 1.41421356f * __cosf(pr);
    }
    __syncthreads();
    float psi = 0.f;
    const float4* eav = (const float4*)ea;
#pragma unroll
    for(int k=0;k<16;k++){ float4 e4 = eav[k]; psi += e4.x*er[k].x + e4.y*er[k].y + e4.z*er[k].z + e4.w*er[k].w; }
    acc += mv[i*HIDh + t] * psi;
  }
  agg[(size_t)node*HIDh + t] = acc * (1.0f/15.0f);
}

// ---------------- K8: MLP + layer scale + residual ----------------
__global__ __launch_bounds__(256) void k_mlp(const float* __restrict__ agg, const float* __restrict__ l1w,
                                             const float* __restrict__ l1b, const float* __restrict__ l2w,
                                             const float* __restrict__ l2b, const float* __restrict__ ls,
                                             const float* __restrict__ values, float* __restrict__ out){
  int node = blockIdx.x, t = threadIdx.x;
  __shared__ float ag[HIDh];
  __shared__ float h1[512];
  if(t < 32) ((float4*)ag)[t] = ((const float4*)(agg + (size_t)node*HIDh))[t];
  __syncthreads();
#pragma unroll
  for(int r=0;r<2;r++){
    int u = t + r*256;
    const float4* wr = (const float4*)(l1w + (size_t)u*HIDh);
    const float4* av = (const float4*)ag;
    float a = l1b[u];
#pragma unroll 4
    for(int k=0;k<32;k++){ float4 w = wr[k], xx = av[k]; a += w.x*xx.x + w.y*xx.y + w.z*xx.z + w.w*xx.w; }
    h1[u] = a / (1.0f + __expf(-a));   // silu
  }
  __syncthreads();
  {
    const float4* wr = (const float4*)(l2w + (size_t)t*512);
    const float4* hv = (const float4*)h1;
    float o = l2b[t];
#pragma unroll 4
    for(int k=0;k<128;k++){ float4 w = wr[k], xx = hv[k]; o += w.x*xx.x + w.y*xx.y + w.z*xx.z + w.w*xx.w; }
    size_t oi = (size_t)node*Ee + t;
    out[oi] = ls[t]*o + values[oi];
  }
}

extern "C" void kernel_launch(void* const* d_in, const int* in_sizes, int n_in,
                              void* d_out, int out_size, void* d_ws, size_t ws_size,
                              hipStream_t stream) {
  const float* x    = (const float*)d_in[0];
  const float* qw   = (const float*)d_in[1];
  const float* qb   = (const float*)d_in[2];
  const float* kw   = (const float*)d_in[3];
  // d_in[4] = kb: adds a per-(b,h) constant to logits -> cancels in softmax; unused.
  const float* vw   = (const float*)d_in[5];
  const float* vb   = (const float*)d_in[6];
  const float* brff = (const float*)d_in[7];
  const float* msgw = (const float*)d_in[8];
  const float* msgb = (const float*)d_in[9];
  const float* embw = (const float*)d_in[10];
  const float* l1w  = (const float*)d_in[11];
  const float* l1b  = (const float*)d_in[12];
  const float* l2w  = (const float*)d_in[13];
  const float* l2b  = (const float*)d_in[14];
  const float* lsc  = (const float*)d_in[15];
  // d_in[16], d_in[17] = edge_src/edge_dst: deterministic fully-connected graph; handled structurally.

  float* W      = (float*)d_ws;
  float* xm     = W;                    // 12288
  float* qkt    = xm  + 12288;          // 196608
  float* lg     = qkt + 196608;         // 2097152 (logits, then attn in-place)
  float* pos    = lg  + 2097152;        // 1024
  float* part   = pos + 1024;           // 16*196608 = 3145728
  float* values = part + 3145728;       // 131072
  float* msgv   = values + 131072;      // 65536
  float* agg    = msgv + 65536;         // 65536  (total ~21.9 MiB)
  float* out    = (float*)d_out;

  k_mean   <<<Bsz*Cc, 256, 0, stream>>>(x, xm);
  k_qk     <<<Bsz, 384, 0, stream>>>(xm, qw, qb, kw, qkt);
  k_logits <<<dim3(16, Bsz), 256, 0, stream>>>(x, qkt, lg);
  k_softmax<<<Bsz*NHh, 256, 0, stream>>>(lg, pos);
  k_xa     <<<dim3(16, Bsz), 256, 0, stream>>>(x, lg, part);
  k_values <<<Bsz*NHh, 256, 0, stream>>>(part, vw, vb, msgw, msgb, values, msgv);
  k_agg    <<<Bsz*NHh, 128, 0, stream>>>(pos, msgv, brff, embw, agg);
  k_mlp    <<<Bsz*NHh, 256, 0, stream>>>(agg, l1w, l1b, l2w, l2b, lsc, values, out);
}